// Round 7
// baseline (593.961 us; speedup 1.0000x reference)
//
#include <hip/hip_runtime.h>
#include <hip/hip_bf16.h>

#define H_DIM 1024
#define I_DIM 2048
#define NE 8
#define NT 4096

typedef __bf16 bf16x8 __attribute__((ext_vector_type(8)));
typedef __bf16 bf16x4 __attribute__((ext_vector_type(4)));
typedef float f32x4 __attribute__((ext_vector_type(4)));

// 16B-chunk index within a [rows][8-chunk] LDS tile, XOR-swizzled (verified
// conflict-free R1-R6: SQ_LDS_BANK_CONFLICT == 0).
__device__ __forceinline__ int swzc(int r, int j) { return r * 8 + (j ^ (r & 7)); }

// async global->LDS, 16B per lane. LDS dest is wave-uniform base (HW adds lane*16).
__device__ __forceinline__ void gl16(const void* g, void* l) {
  __builtin_amdgcn_global_load_lds(
      (const __attribute__((address_space(1))) unsigned int*)g,
      (__attribute__((address_space(3))) unsigned int*)l, 16, 0, 0);
}

__device__ __forceinline__ bf16x8 cvt8(float4 a, float4 b) {
  bf16x8 r;
  r[0] = (__bf16)a.x; r[1] = (__bf16)a.y; r[2] = (__bf16)a.z; r[3] = (__bf16)a.w;
  r[4] = (__bf16)b.x; r[5] = (__bf16)b.y; r[6] = (__bf16)b.z; r[7] = (__bf16)b.w;
  return r;
}

// One-shot cast of all six weight matrices fp32->bf16 (pow2 region sizes).
__global__ __launch_bounds__(256) void k_castall(
    const float* __restrict__ wg, const float* __restrict__ wu,
    const float* __restrict__ wd, const float* __restrict__ sg,
    const float* __restrict__ su, const float* __restrict__ sd,
    __bf16* __restrict__ wgb, __bf16* __restrict__ wub, __bf16* __restrict__ wdb,
    __bf16* __restrict__ sgb, __bf16* __restrict__ sub, __bf16* __restrict__ sdb) {
  long long i = (long long)blockIdx.x * 256 + threadIdx.x;
  const long long NW = 1LL << 21, NS = 1LL << 18;
  const float* s; __bf16* d; int off;
  if (i < 3 * NW) {
    int r = (int)(i >> 21); off = (int)(i & (NW - 1));
    s = (r == 0) ? wg : (r == 1) ? wu : wd;
    d = (r == 0) ? wgb : (r == 1) ? wub : wdb;
  } else {
    long long j = i - 3 * NW;
    int r = (int)(j >> 18); off = (int)(j & (NS - 1));
    s = (r == 0) ? sg : (r == 1) ? su : sd;
    d = (r == 0) ? sgb : (r == 1) ? sub : sdb;
  }
  const float4* s4 = (const float4*)s;
  float4 a = s4[(size_t)off * 2], b = s4[(size_t)off * 2 + 1];
  ((bf16x8*)d)[off] = cvt8(a, b);
}

// Router: sigmoid top-2 renorm + per-expert token lists; fuses x -> bf16 cast.
__global__ __launch_bounds__(256) void k_router(const float* __restrict__ x,
                                                const float* __restrict__ rw,
                                                const float* __restrict__ rbias,
                                                __bf16* __restrict__ xb,
                                                int* __restrict__ counts,
                                                int* __restrict__ list,
                                                int* __restrict__ tE,
                                                int* __restrict__ tP,
                                                float* __restrict__ tG) {
  int wv = threadIdx.x >> 6, lane = threadIdx.x & 63;
  int t = blockIdx.x * 4 + wv;
  float acc[NE];
#pragma unroll
  for (int e = 0; e < NE; e++) acc[e] = 0.f;
  const float4* xr = (const float4*)(x + (size_t)t * H_DIM);
  const float4* wr4 = (const float4*)rw;
  bf16x4* xo = (bf16x4*)xb + (size_t)t * (H_DIM / 4);
#pragma unroll
  for (int it = 0; it < 4; ++it) {
    int c = it * 64 + lane;
    float4 xv = xr[c];
    bf16x4 bv;
    bv[0] = (__bf16)xv.x; bv[1] = (__bf16)xv.y;
    bv[2] = (__bf16)xv.z; bv[3] = (__bf16)xv.w;
    xo[c] = bv;
#pragma unroll
    for (int e = 0; e < NE; e++) {
      float4 wv = wr4[e * (H_DIM / 4) + c];
      acc[e] += xv.x * wv.x + xv.y * wv.y + xv.z * wv.z + xv.w * wv.w;
    }
  }
#pragma unroll
  for (int e = 0; e < NE; e++) {
#pragma unroll
    for (int off = 32; off > 0; off >>= 1) acc[e] += __shfl_xor(acc[e], off, 64);
  }
  if (lane == 0) {
    float p[NE];
#pragma unroll
    for (int e = 0; e < NE; e++) p[e] = 1.f / (1.f + expf(-(acc[e] + rbias[e])));
    int e0 = 0;
#pragma unroll
    for (int e = 1; e < NE; e++) if (p[e] > p[e0]) e0 = e;
    int e1 = -1;
#pragma unroll
    for (int e = 0; e < NE; e++) if (e != e0 && (e1 < 0 || p[e] > p[e1])) e1 = e;
    float s = p[e0] + p[e1];
    float g0 = p[e0] / s, g1 = p[e1] / s;
    int p0 = atomicAdd(&counts[e0], 1);
    int p1 = atomicAdd(&counts[e1], 1);
    list[e0 * NT + p0] = t;
    list[e1 * NT + p1] = t;
    tE[t * 2] = e0; tE[t * 2 + 1] = e1;
    tP[t * 2] = p0; tP[t * 2 + 1] = p1;
    tG[t * 2] = g0; tG[t * 2 + 1] = g1;
  }
}

// ---------------------------------------------------------------------------
// Fused gate+up GEMM (R3 measured-best loop). Tile: 256 rows x 128 i-cols
// (g and u panels), BK=64, 8 waves, 128 KB dbuf LDS.
// Grid: 1D 2304 with bijective XCD-chunk swizzle, m INNERMOST so consecutive
// same-XCD blocks share the (z,n) weight panel in their XCD's L2.
// ---------------------------------------------------------------------------
__global__ __launch_bounds__(512, 2) void k_upgate8(
    const __bf16* __restrict__ xb, const __bf16* __restrict__ wgb,
    const __bf16* __restrict__ wub, const __bf16* __restrict__ sgb,
    const __bf16* __restrict__ sub, const int* __restrict__ counts,
    const int* __restrict__ list,
    __bf16* __restrict__ hs, __bf16* __restrict__ hr) {
  // nwg = 9z * 16n * 16m = 2304; wgid = z*256 + n*16 + m (m innermost)
  int orig = blockIdx.x;
  int wgid = (orig & 7) * 288 + (orig >> 3);   // 2304/8 = 288, bijective
  int z = wgid >> 8;
  int rem = wgid & 255;
  int n0 = (rem >> 4) * 128, m0 = (rem & 15) * 256;
  bool sh = (z == NE);
  int count, base = 0;
  const __bf16 *Bg, *Bu;
  if (sh) {
    count = NT; Bg = sgb; Bu = sub;
  } else {
    count = counts[z];
    if (m0 >= count) return;
    for (int e = 0; e < z; e++) base += counts[e];
    Bg = wgb + (size_t)z * (I_DIM * H_DIM);
    Bu = wub + (size_t)z * (I_DIM * H_DIM);
  }

  __shared__ bf16x8 lds[8192];              // 128 KB
  bf16x8* sA  = lds;                        // [2][2048]  A: 256 rows x 8 chunks
  bf16x8* sBg = lds + 4096;                 // [2][1024]  Bg: 128 x 8
  bf16x8* sBu = lds + 6144;                 // [2][1024]

  int tid = threadIdx.x, lane = tid & 63, w = tid >> 6;
  int wm = w >> 2, wn = w & 3;
  int fr = lane & 15, fs = lane >> 4;

  int srcA[4], srcB[2];
#pragma unroll
  for (int q = 0; q < 4; q++) {
    int c = q * 512 + tid;
    int r = c >> 3, j = (c & 7) ^ (r & 7);
    int gr = m0 + r;
    int tok = sh ? gr : ((gr < count) ? list[z * NT + gr] : list[z * NT]);
    srcA[q] = tok * (H_DIM / 8) + j;
  }
#pragma unroll
  for (int q = 0; q < 2; q++) {
    int c = q * 512 + tid;
    int r = c >> 3, j = (c & 7) ^ (r & 7);
    srcB[q] = (n0 + r) * (H_DIM / 8) + j;
  }

  const bf16x8* a8 = (const bf16x8*)xb;
  const bf16x8* g8 = (const bf16x8*)Bg;
  const bf16x8* u8 = (const bf16x8*)Bu;

  f32x4 accg[8][2], accu[8][2];
#pragma unroll
  for (int m = 0; m < 8; m++)
#pragma unroll
    for (int n = 0; n < 2; n++) {
      accg[m][n] = (f32x4){0.f, 0.f, 0.f, 0.f};
      accu[m][n] = (f32x4){0.f, 0.f, 0.f, 0.f};
    }

  // prologue: stage K-tile 0 into buffer 0
#pragma unroll
  for (int q = 0; q < 4; q++) gl16(a8 + srcA[q], sA + q * 512 + w * 64);
#pragma unroll
  for (int q = 0; q < 2; q++) {
    gl16(g8 + srcB[q], sBg + q * 512 + w * 64);
    gl16(u8 + srcB[q], sBu + q * 512 + w * 64);
  }
  __syncthreads();

  for (int kt = 0; kt < H_DIM / 64; ++kt) {
    int cur = kt & 1, nxt = cur ^ 1;
    const bf16x8* A = sA + cur * 2048;
    const bf16x8* G = sBg + cur * 1024;
    const bf16x8* U = sBu + cur * 1024;
    bf16x8* dA = sA + nxt * 2048;
    bf16x8* dG = sBg + nxt * 1024;
    bf16x8* dU = sBu + nxt * 1024;
    bool pf = (kt + 1 < H_DIM / 64);
    int ko = (kt + 1) * 8;

    bf16x8 bg[2][2], bu[2][2];
#pragma unroll
    for (int p = 0; p < 4; ++p) {
      bf16x8 af[2][2];
#pragma unroll
      for (int m2 = 0; m2 < 2; m2++)
#pragma unroll
        for (int ks = 0; ks < 2; ks++)
          af[m2][ks] = A[swzc(wm * 128 + (p * 2 + m2) * 16 + fr, ks * 4 + fs)];
      if (p == 0) {
#pragma unroll
        for (int n = 0; n < 2; n++)
#pragma unroll
          for (int ks = 0; ks < 2; ks++) {
            bg[n][ks] = G[swzc(wn * 32 + n * 16 + fr, ks * 4 + fs)];
            bu[n][ks] = U[swzc(wn * 32 + n * 16 + fr, ks * 4 + fs)];
          }
      }
      if (pf) {
        if (p == 0) {
          gl16(a8 + srcA[0] + ko, dA + 0 * 512 + w * 64);
          gl16(a8 + srcA[1] + ko, dA + 1 * 512 + w * 64);
        } else if (p == 1) {
          gl16(a8 + srcA[2] + ko, dA + 2 * 512 + w * 64);
          gl16(a8 + srcA[3] + ko, dA + 3 * 512 + w * 64);
        } else if (p == 2) {
          gl16(g8 + srcB[0] + ko, dG + 0 * 512 + w * 64);
          gl16(g8 + srcB[1] + ko, dG + 1 * 512 + w * 64);
        } else {
          gl16(u8 + srcB[0] + ko, dU + 0 * 512 + w * 64);
          gl16(u8 + srcB[1] + ko, dU + 1 * 512 + w * 64);
        }
      }
      __builtin_amdgcn_s_setprio(1);
#pragma unroll
      for (int m2 = 0; m2 < 2; m2++)
#pragma unroll
        for (int n = 0; n < 2; n++)
#pragma unroll
          for (int ks = 0; ks < 2; ks++) {
            int m = p * 2 + m2;
            accg[m][n] = __builtin_amdgcn_mfma_f32_16x16x32_bf16(af[m2][ks], bg[n][ks], accg[m][n], 0, 0, 0);
            accu[m][n] = __builtin_amdgcn_mfma_f32_16x16x32_bf16(af[m2][ks], bu[n][ks], accu[m][n], 0, 0, 0);
          }
      __builtin_amdgcn_s_setprio(0);
    }
    __syncthreads();
  }

#pragma unroll
  for (int m = 0; m < 8; m++)
#pragma unroll
    for (int n = 0; n < 2; n++)
#pragma unroll
      for (int q2 = 0; q2 < 4; q2++) {
        int row = wm * 128 + m * 16 + fs * 4 + q2;
        int col = n0 + wn * 32 + n * 16 + fr;
        float g = accg[m][n][q2], u = accu[m][n][q2];
        float h = g * u / (1.f + expf(-g));  // silu(g)*u
        __bf16 hb = (__bf16)h;
        int grow = m0 + row;
        if (sh) hs[(size_t)grow * I_DIM + col] = hb;
        else if (grow < count) hr[(size_t)(base + grow) * I_DIM + col] = hb;
      }
}

// ---------------------------------------------------------------------------
// Down GEMM, m97 config: 128x128 tile, BK=64, 4 waves (2x2), 64 KB dbuf LDS
// -> 2 blocks/CU (cross-block latency hiding). Grid 2304 (9z*8n*32m),
// m-innermost XCD swizzle.
// ---------------------------------------------------------------------------
__global__ __launch_bounds__(256, 2) void k_down97(
    const __bf16* __restrict__ hs, const __bf16* __restrict__ hr,
    const __bf16* __restrict__ wdb, const __bf16* __restrict__ sdb,
    const int* __restrict__ counts,
    float* __restrict__ out, float* __restrict__ y) {
  // nwg = 9z * 8n * 32m = 2304; wgid = z*256 + n*32 + m
  int orig = blockIdx.x;
  int wgid = (orig & 7) * 288 + (orig >> 3);
  int z = wgid >> 8;
  int rem = wgid & 255;
  int n0 = (rem >> 5) * 128, m0 = (rem & 31) * 128;
  bool sh = (z == NE);
  int count, base = 0;
  const __bf16 *B, *A;
  if (sh) {
    count = NT; B = sdb; A = hs;
  } else {
    count = counts[z];
    if (m0 >= count) return;
    for (int e = 0; e < z; e++) base += counts[e];
    B = wdb + (size_t)z * (H_DIM * I_DIM);
    A = hr + (size_t)base * I_DIM;
  }

  __shared__ bf16x8 lds[4096];   // [2][A 1024 | B 1024] = 64 KB

  int tid = threadIdx.x, lane = tid & 63, w = tid >> 6;
  int wr = w >> 1, wc = w & 1;
  int fr = lane & 15, fs = lane >> 4;

  const bf16x8* a8 = (const bf16x8*)A;
  const bf16x8* b8 = (const bf16x8*)B;

  const bf16x8* pA[4];
  const bf16x8* pB[4];
#pragma unroll
  for (int q = 0; q < 4; q++) {
    int c = q * 256 + tid;                  // chunk 0..1023 (128 rows x 8)
    int r = c >> 3, j = (c & 7) ^ (r & 7);
    int ra = m0 + r; if (ra >= count) ra = count - 1;
    pA[q] = a8 + (size_t)ra * (I_DIM / 8) + j;
    pB[q] = b8 + (size_t)(n0 + r) * (I_DIM / 8) + j;
  }

  f32x4 acc[4][4];
#pragma unroll
  for (int m = 0; m < 4; m++)
#pragma unroll
    for (int n = 0; n < 4; n++) acc[m][n] = (f32x4){0.f, 0.f, 0.f, 0.f};

  // prologue: stage tile 0 into buf 0
  {
    bf16x8* dA = lds;
    bf16x8* dB = lds + 1024;
#pragma unroll
    for (int q = 0; q < 4; q++) {
      gl16(pA[q], dA + q * 256 + w * 64);
      gl16(pB[q], dB + q * 256 + w * 64);
    }
  }

  const int NK = I_DIM / 64;  // 32
  for (int kt = 0; kt < NK; ++kt) {
    __syncthreads();           // drains tile kt's loads; WAR-fences buf^1
    if (kt + 1 < NK) {
      bf16x8* dA = lds + ((kt + 1) & 1) * 2048;
      bf16x8* dB = dA + 1024;
      int ko = (kt + 1) * 8;
#pragma unroll
      for (int q = 0; q < 4; q++) {
        gl16(pA[q] + ko, dA + q * 256 + w * 64);
        gl16(pB[q] + ko, dB + q * 256 + w * 64);
      }
    }
    const bf16x8* Ac = lds + (kt & 1) * 2048;
    const bf16x8* Bc = Ac + 1024;
#pragma unroll
    for (int ks = 0; ks < 2; ks++) {
      bf16x8 af[4], bfr[4];
#pragma unroll
      for (int mf = 0; mf < 4; mf++) af[mf] = Ac[swzc(wr * 64 + mf * 16 + fr, ks * 4 + fs)];
#pragma unroll
      for (int nf = 0; nf < 4; nf++) bfr[nf] = Bc[swzc(wc * 64 + nf * 16 + fr, ks * 4 + fs)];
      __builtin_amdgcn_s_setprio(1);
#pragma unroll
      for (int m = 0; m < 4; m++)
#pragma unroll
        for (int n = 0; n < 4; n++)
          acc[m][n] = __builtin_amdgcn_mfma_f32_16x16x32_bf16(af[m], bfr[n], acc[m][n], 0, 0, 0);
      __builtin_amdgcn_s_setprio(0);
    }
  }

#pragma unroll
  for (int m = 0; m < 4; m++)
#pragma unroll
    for (int n = 0; n < 4; n++)
#pragma unroll
      for (int q2 = 0; q2 < 4; q2++) {
        int row = wr * 64 + m * 16 + fs * 4 + q2;
        int col = n0 + wc * 64 + n * 16 + fr;
        float v = acc[m][n][q2];
        int grow = m0 + row;
        if (sh) out[(size_t)grow * H_DIM + col] = v;
        else if (grow < count) y[(size_t)(base + grow) * H_DIM + col] = v;
      }
}

__global__ __launch_bounds__(256) void k_combine(
    const float* __restrict__ y, const int* __restrict__ counts,
    const int* __restrict__ tE, const int* __restrict__ tP,
    const float* __restrict__ tG, float* __restrict__ out) {
  int t = blockIdx.x;
  int c = threadIdx.x;  // H/4 = 256 float4 per token row
  int bases[NE];
  int s = 0;
#pragma unroll
  for (int e = 0; e < NE; e++) { bases[e] = s; s += counts[e]; }
  int e0 = tE[t * 2], e1 = tE[t * 2 + 1];
  int r0 = bases[e0] + tP[t * 2], r1 = bases[e1] + tP[t * 2 + 1];
  float g0 = tG[t * 2], g1 = tG[t * 2 + 1];
  const float4* y4 = (const float4*)y;
  float4* o4 = (float4*)out;
  float4 sv = o4[(size_t)t * (H_DIM / 4) + c];
  float4 a = y4[(size_t)r0 * (H_DIM / 4) + c];
  float4 b = y4[(size_t)r1 * (H_DIM / 4) + c];
  sv.x += g0 * a.x + g1 * b.x;
  sv.y += g0 * a.y + g1 * b.y;
  sv.z += g0 * a.z + g1 * b.z;
  sv.w += g0 * a.w + g1 * b.w;
  o4[(size_t)t * (H_DIM / 4) + c] = sv;
}

extern "C" void kernel_launch(void* const* d_in, const int* in_sizes, int n_in,
                              void* d_out, int out_size, void* d_ws, size_t ws_size,
                              hipStream_t stream) {
  const float* x = (const float*)d_in[0];
  const float* sg_w = (const float*)d_in[1];
  const float* su_w = (const float*)d_in[2];
  const float* sd_w = (const float*)d_in[3];
  const float* router_w = (const float*)d_in[4];
  const float* routing_bias = (const float*)d_in[5];
  const float* wg = (const float*)d_in[6];
  const float* wu = (const float*)d_in[7];
  const float* wd = (const float*)d_in[8];
  float* out = (float*)d_out;
  char* ws = (char*)d_ws;

  __bf16* xb  = (__bf16*)(ws + 0);            //  8,388,608
  __bf16* hs  = (__bf16*)(ws + 8388608);      // 16,777,216
  __bf16* hr  = (__bf16*)(ws + 25165824);     // 33,554,432
  float*  y   = (float*)(ws + 58720256);      // 33,554,432
  __bf16* wgb = (__bf16*)(ws + 92274688);     // 33,554,432
  __bf16* wub = (__bf16*)(ws + 125829120);    // 33,554,432
  __bf16* wdb = (__bf16*)(ws + 159383552);    // 33,554,432
  __bf16* sgb = (__bf16*)(ws + 192937984);    //  4,194,304
  __bf16* sub = (__bf16*)(ws + 197132288);    //  4,194,304
  __bf16* sdb = (__bf16*)(ws + 201326592);    //  4,194,304
  int* counts = (int*)(ws + 205520896);
  int* list   = (int*)(ws + 205520960);       // 131,072
  int* tE     = (int*)(ws + 205652032);       // 32,768
  int* tP     = (int*)(ws + 205684800);       // 32,768
  float* tG   = (float*)(ws + 205717568);     // 32,768

  hipMemsetAsync(counts, 0, NE * sizeof(int), stream);
  k_castall<<<27648, 256, 0, stream>>>(wg, wu, wd, sg_w, su_w, sd_w,
                                       wgb, wub, wdb, sgb, sub, sdb);
  k_router<<<NT / 4, 256, 0, stream>>>(x, router_w, routing_bias, xb,
                                       counts, list, tE, tP, tG);
  k_upgate8<<<2304, 512, 0, stream>>>(xb, wgb, wub, sgb, sub, counts, list, hs, hr);
  k_down97<<<2304, 256, 0, stream>>>(hs, hr, wdb, sdb, counts, out, y);
  k_combine<<<NT, 256, 0, stream>>>(y, counts, tE, tP, tG, out);
}

// Round 8
// 390.375 us; speedup vs baseline: 1.5215x; 1.5215x over previous
//
#include <hip/hip_runtime.h>
#include <hip/hip_bf16.h>

#define H_DIM 1024
#define I_DIM 2048
#define NE 8
#define NT 4096

typedef __bf16 bf16x8 __attribute__((ext_vector_type(8)));
typedef __bf16 bf16x4 __attribute__((ext_vector_type(4)));
typedef float f32x4 __attribute__((ext_vector_type(4)));

// 16B-chunk index within a [rows][8-chunk] LDS tile, XOR-swizzled (verified
// conflict-free R1-R7: SQ_LDS_BANK_CONFLICT == 0).
__device__ __forceinline__ int swzc(int r, int j) { return r * 8 + (j ^ (r & 7)); }

// async global->LDS, 16B per lane. LDS dest is wave-uniform base (HW adds lane*16).
__device__ __forceinline__ void gl16(const void* g, void* l) {
  __builtin_amdgcn_global_load_lds(
      (const __attribute__((address_space(1))) unsigned int*)g,
      (__attribute__((address_space(3))) unsigned int*)l, 16, 0, 0);
}

__device__ __forceinline__ bf16x8 cvt8(float4 a, float4 b) {
  bf16x8 r;
  r[0] = (__bf16)a.x; r[1] = (__bf16)a.y; r[2] = (__bf16)a.z; r[3] = (__bf16)a.w;
  r[4] = (__bf16)b.x; r[5] = (__bf16)b.y; r[6] = (__bf16)b.z; r[7] = (__bf16)b.w;
  return r;
}

// One-shot cast of all six weight matrices fp32->bf16 (pow2 region sizes).
__global__ __launch_bounds__(256) void k_castall(
    const float* __restrict__ wg, const float* __restrict__ wu,
    const float* __restrict__ wd, const float* __restrict__ sg,
    const float* __restrict__ su, const float* __restrict__ sd,
    __bf16* __restrict__ wgb, __bf16* __restrict__ wub, __bf16* __restrict__ wdb,
    __bf16* __restrict__ sgb, __bf16* __restrict__ sub, __bf16* __restrict__ sdb) {
  long long i = (long long)blockIdx.x * 256 + threadIdx.x;
  const long long NW = 1LL << 21, NS = 1LL << 18;
  const float* s; __bf16* d; int off;
  if (i < 3 * NW) {
    int r = (int)(i >> 21); off = (int)(i & (NW - 1));
    s = (r == 0) ? wg : (r == 1) ? wu : wd;
    d = (r == 0) ? wgb : (r == 1) ? wub : wdb;
  } else {
    long long j = i - 3 * NW;
    int r = (int)(j >> 18); off = (int)(j & (NS - 1));
    s = (r == 0) ? sg : (r == 1) ? su : sd;
    d = (r == 0) ? sgb : (r == 1) ? sub : sdb;
  }
  const float4* s4 = (const float4*)s;
  float4 a = s4[(size_t)off * 2], b = s4[(size_t)off * 2 + 1];
  ((bf16x8*)d)[off] = cvt8(a, b);
}

// Router: sigmoid top-2 renorm + per-expert token lists; fuses x -> bf16 cast.
__global__ __launch_bounds__(256) void k_router(const float* __restrict__ x,
                                                const float* __restrict__ rw,
                                                const float* __restrict__ rbias,
                                                __bf16* __restrict__ xb,
                                                int* __restrict__ counts,
                                                int* __restrict__ list,
                                                int* __restrict__ tE,
                                                int* __restrict__ tP,
                                                float* __restrict__ tG) {
  int wv = threadIdx.x >> 6, lane = threadIdx.x & 63;
  int t = blockIdx.x * 4 + wv;
  float acc[NE];
#pragma unroll
  for (int e = 0; e < NE; e++) acc[e] = 0.f;
  const float4* xr = (const float4*)(x + (size_t)t * H_DIM);
  const float4* wr4 = (const float4*)rw;
  bf16x4* xo = (bf16x4*)xb + (size_t)t * (H_DIM / 4);
#pragma unroll
  for (int it = 0; it < 4; ++it) {
    int c = it * 64 + lane;
    float4 xv = xr[c];
    bf16x4 bv;
    bv[0] = (__bf16)xv.x; bv[1] = (__bf16)xv.y;
    bv[2] = (__bf16)xv.z; bv[3] = (__bf16)xv.w;
    xo[c] = bv;
#pragma unroll
    for (int e = 0; e < NE; e++) {
      float4 wv = wr4[e * (H_DIM / 4) + c];
      acc[e] += xv.x * wv.x + xv.y * wv.y + xv.z * wv.z + xv.w * wv.w;
    }
  }
#pragma unroll
  for (int e = 0; e < NE; e++) {
#pragma unroll
    for (int off = 32; off > 0; off >>= 1) acc[e] += __shfl_xor(acc[e], off, 64);
  }
  if (lane == 0) {
    float p[NE];
#pragma unroll
    for (int e = 0; e < NE; e++) p[e] = 1.f / (1.f + expf(-(acc[e] + rbias[e])));
    int e0 = 0;
#pragma unroll
    for (int e = 1; e < NE; e++) if (p[e] > p[e0]) e0 = e;
    int e1 = -1;
#pragma unroll
    for (int e = 0; e < NE; e++) if (e != e0 && (e1 < 0 || p[e] > p[e1])) e1 = e;
    float s = p[e0] + p[e1];
    float g0 = p[e0] / s, g1 = p[e1] / s;
    int p0 = atomicAdd(&counts[e0], 1);
    int p1 = atomicAdd(&counts[e1], 1);
    list[e0 * NT + p0] = t;
    list[e1 * NT + p1] = t;
    tE[t * 2] = e0; tE[t * 2 + 1] = e1;
    tP[t * 2] = p0; tP[t * 2 + 1] = p1;
    tG[t * 2] = g0; tG[t * 2 + 1] = g1;
  }
}

// ---------------------------------------------------------------------------
// Fused gate+up GEMM — R3 measured-best structure, dim3 grid (n fastest, NO
// XCD swizzle: m-innermost swizzle reproduced a 2x regression in R5 and R7).
// Tile: 256 rows x 128 cols (dual g/u acc), BK=64, 8 waves, 128 KB dbuf LDS.
// ---------------------------------------------------------------------------
__global__ __launch_bounds__(512, 2) void k_upgate8(
    const __bf16* __restrict__ xb, const __bf16* __restrict__ wgb,
    const __bf16* __restrict__ wub, const __bf16* __restrict__ sgb,
    const __bf16* __restrict__ sub, const int* __restrict__ counts,
    const int* __restrict__ list,
    __bf16* __restrict__ hs, __bf16* __restrict__ hr) {
  int z = blockIdx.z;
  int m0 = blockIdx.y * 256, n0 = blockIdx.x * 128;
  bool sh = (z == NE);
  int count, base = 0;
  const __bf16 *Bg, *Bu;
  if (sh) {
    count = NT; Bg = sgb; Bu = sub;
  } else {
    count = counts[z];
    if (m0 >= count) return;
    for (int e = 0; e < z; e++) base += counts[e];
    Bg = wgb + (size_t)z * (I_DIM * H_DIM);
    Bu = wub + (size_t)z * (I_DIM * H_DIM);
  }

  __shared__ bf16x8 lds[8192];              // 128 KB
  bf16x8* sA  = lds;                        // [2][2048]  A: 256 rows x 8 chunks
  bf16x8* sBg = lds + 4096;                 // [2][1024]  Bg: 128 x 8
  bf16x8* sBu = lds + 6144;                 // [2][1024]

  int tid = threadIdx.x, lane = tid & 63, w = tid >> 6;
  int wm = w >> 2, wn = w & 3;
  int fr = lane & 15, fs = lane >> 4;

  int srcA[4], srcB[2];
#pragma unroll
  for (int q = 0; q < 4; q++) {
    int c = q * 512 + tid;
    int r = c >> 3, j = (c & 7) ^ (r & 7);
    int gr = m0 + r;
    int tok = sh ? gr : ((gr < count) ? list[z * NT + gr] : list[z * NT]);
    srcA[q] = tok * (H_DIM / 8) + j;
  }
#pragma unroll
  for (int q = 0; q < 2; q++) {
    int c = q * 512 + tid;
    int r = c >> 3, j = (c & 7) ^ (r & 7);
    srcB[q] = (n0 + r) * (H_DIM / 8) + j;
  }

  const bf16x8* a8 = (const bf16x8*)xb;
  const bf16x8* g8 = (const bf16x8*)Bg;
  const bf16x8* u8 = (const bf16x8*)Bu;

  f32x4 accg[8][2], accu[8][2];
#pragma unroll
  for (int m = 0; m < 8; m++)
#pragma unroll
    for (int n = 0; n < 2; n++) {
      accg[m][n] = (f32x4){0.f, 0.f, 0.f, 0.f};
      accu[m][n] = (f32x4){0.f, 0.f, 0.f, 0.f};
    }

  // prologue: stage K-tile 0 into buffer 0
#pragma unroll
  for (int q = 0; q < 4; q++) gl16(a8 + srcA[q], sA + q * 512 + w * 64);
#pragma unroll
  for (int q = 0; q < 2; q++) {
    gl16(g8 + srcB[q], sBg + q * 512 + w * 64);
    gl16(u8 + srcB[q], sBu + q * 512 + w * 64);
  }
  __syncthreads();

  for (int kt = 0; kt < H_DIM / 64; ++kt) {
    int cur = kt & 1, nxt = cur ^ 1;
    const bf16x8* A = sA + cur * 2048;
    const bf16x8* G = sBg + cur * 1024;
    const bf16x8* U = sBu + cur * 1024;
    bf16x8* dA = sA + nxt * 2048;
    bf16x8* dG = sBg + nxt * 1024;
    bf16x8* dU = sBu + nxt * 1024;
    bool pf = (kt + 1 < H_DIM / 64);
    int ko = (kt + 1) * 8;

    bf16x8 bg[2][2], bu[2][2];
#pragma unroll
    for (int p = 0; p < 4; ++p) {
      bf16x8 af[2][2];
#pragma unroll
      for (int m2 = 0; m2 < 2; m2++)
#pragma unroll
        for (int ks = 0; ks < 2; ks++)
          af[m2][ks] = A[swzc(wm * 128 + (p * 2 + m2) * 16 + fr, ks * 4 + fs)];
      if (p == 0) {
#pragma unroll
        for (int n = 0; n < 2; n++)
#pragma unroll
          for (int ks = 0; ks < 2; ks++) {
            bg[n][ks] = G[swzc(wn * 32 + n * 16 + fr, ks * 4 + fs)];
            bu[n][ks] = U[swzc(wn * 32 + n * 16 + fr, ks * 4 + fs)];
          }
      }
      if (pf) {
        if (p == 0) {
          gl16(a8 + srcA[0] + ko, dA + 0 * 512 + w * 64);
          gl16(a8 + srcA[1] + ko, dA + 1 * 512 + w * 64);
        } else if (p == 1) {
          gl16(a8 + srcA[2] + ko, dA + 2 * 512 + w * 64);
          gl16(a8 + srcA[3] + ko, dA + 3 * 512 + w * 64);
        } else if (p == 2) {
          gl16(g8 + srcB[0] + ko, dG + 0 * 512 + w * 64);
          gl16(g8 + srcB[1] + ko, dG + 1 * 512 + w * 64);
        } else {
          gl16(u8 + srcB[0] + ko, dU + 0 * 512 + w * 64);
          gl16(u8 + srcB[1] + ko, dU + 1 * 512 + w * 64);
        }
      }
      __builtin_amdgcn_s_setprio(1);
#pragma unroll
      for (int m2 = 0; m2 < 2; m2++)
#pragma unroll
        for (int n = 0; n < 2; n++)
#pragma unroll
          for (int ks = 0; ks < 2; ks++) {
            int m = p * 2 + m2;
            accg[m][n] = __builtin_amdgcn_mfma_f32_16x16x32_bf16(af[m2][ks], bg[n][ks], accg[m][n], 0, 0, 0);
            accu[m][n] = __builtin_amdgcn_mfma_f32_16x16x32_bf16(af[m2][ks], bu[n][ks], accu[m][n], 0, 0, 0);
          }
      __builtin_amdgcn_s_setprio(0);
    }
    __syncthreads();
  }

#pragma unroll
  for (int m = 0; m < 8; m++)
#pragma unroll
    for (int n = 0; n < 2; n++)
#pragma unroll
      for (int q2 = 0; q2 < 4; q2++) {
        int row = wm * 128 + m * 16 + fs * 4 + q2;
        int col = n0 + wn * 32 + n * 16 + fr;
        float g = accg[m][n][q2], u = accu[m][n][q2];
        float h = g * u / (1.f + expf(-g));  // silu(g)*u
        __bf16 hb = (__bf16)h;
        int grow = m0 + row;
        if (sh) hs[(size_t)grow * I_DIM + col] = hb;
        else if (grow < count) hr[(size_t)(base + grow) * I_DIM + col] = hb;
      }
}

// ---------------------------------------------------------------------------
// Down GEMM, m97 config: 128x128 tile, BK=64, 4 waves (2x2), 64 KB dbuf LDS
// -> 2 blocks/CU (cross-block latency hiding). dim3 grid (n=8, m=32, z=9),
// n fastest, NO swizzle.
// ---------------------------------------------------------------------------
__global__ __launch_bounds__(256, 2) void k_down97(
    const __bf16* __restrict__ hs, const __bf16* __restrict__ hr,
    const __bf16* __restrict__ wdb, const __bf16* __restrict__ sdb,
    const int* __restrict__ counts,
    float* __restrict__ out, float* __restrict__ y) {
  int z = blockIdx.z;
  int m0 = blockIdx.y * 128, n0 = blockIdx.x * 128;
  bool sh = (z == NE);
  int count, base = 0;
  const __bf16 *B, *A;
  if (sh) {
    count = NT; B = sdb; A = hs;
  } else {
    count = counts[z];
    if (m0 >= count) return;
    for (int e = 0; e < z; e++) base += counts[e];
    B = wdb + (size_t)z * (H_DIM * I_DIM);
    A = hr + (size_t)base * I_DIM;
  }

  __shared__ bf16x8 lds[4096];   // [2][A 1024 | B 1024] = 64 KB

  int tid = threadIdx.x, lane = tid & 63, w = tid >> 6;
  int wr = w >> 1, wc = w & 1;
  int fr = lane & 15, fs = lane >> 4;

  const bf16x8* a8 = (const bf16x8*)A;
  const bf16x8* b8 = (const bf16x8*)B;

  const bf16x8* pA[4];
  const bf16x8* pB[4];
#pragma unroll
  for (int q = 0; q < 4; q++) {
    int c = q * 256 + tid;                  // chunk 0..1023 (128 rows x 8)
    int r = c >> 3, j = (c & 7) ^ (r & 7);
    int ra = m0 + r; if (ra >= count) ra = count - 1;
    pA[q] = a8 + (size_t)ra * (I_DIM / 8) + j;
    pB[q] = b8 + (size_t)(n0 + r) * (I_DIM / 8) + j;
  }

  f32x4 acc[4][4];
#pragma unroll
  for (int m = 0; m < 4; m++)
#pragma unroll
    for (int n = 0; n < 4; n++) acc[m][n] = (f32x4){0.f, 0.f, 0.f, 0.f};

  // prologue: stage tile 0 into buf 0
  {
    bf16x8* dA = lds;
    bf16x8* dB = lds + 1024;
#pragma unroll
    for (int q = 0; q < 4; q++) {
      gl16(pA[q], dA + q * 256 + w * 64);
      gl16(pB[q], dB + q * 256 + w * 64);
    }
  }

  const int NK = I_DIM / 64;  // 32
  for (int kt = 0; kt < NK; ++kt) {
    __syncthreads();           // drains tile kt's loads; WAR-fences buf^1
    if (kt + 1 < NK) {
      bf16x8* dA = lds + ((kt + 1) & 1) * 2048;
      bf16x8* dB = dA + 1024;
      int ko = (kt + 1) * 8;
#pragma unroll
      for (int q = 0; q < 4; q++) {
        gl16(pA[q] + ko, dA + q * 256 + w * 64);
        gl16(pB[q] + ko, dB + q * 256 + w * 64);
      }
    }
    const bf16x8* Ac = lds + (kt & 1) * 2048;
    const bf16x8* Bc = Ac + 1024;
#pragma unroll
    for (int ks = 0; ks < 2; ks++) {
      bf16x8 af[4], bfr[4];
#pragma unroll
      for (int mf = 0; mf < 4; mf++) af[mf] = Ac[swzc(wr * 64 + mf * 16 + fr, ks * 4 + fs)];
#pragma unroll
      for (int nf = 0; nf < 4; nf++) bfr[nf] = Bc[swzc(wc * 64 + nf * 16 + fr, ks * 4 + fs)];
      __builtin_amdgcn_s_setprio(1);
#pragma unroll
      for (int m = 0; m < 4; m++)
#pragma unroll
        for (int n = 0; n < 4; n++)
          acc[m][n] = __builtin_amdgcn_mfma_f32_16x16x32_bf16(af[m], bfr[n], acc[m][n], 0, 0, 0);
      __builtin_amdgcn_s_setprio(0);
    }
  }

#pragma unroll
  for (int m = 0; m < 4; m++)
#pragma unroll
    for (int n = 0; n < 4; n++)
#pragma unroll
      for (int q2 = 0; q2 < 4; q2++) {
        int row = wr * 64 + m * 16 + fs * 4 + q2;
        int col = n0 + wc * 64 + n * 16 + fr;
        float v = acc[m][n][q2];
        int grow = m0 + row;
        if (sh) out[(size_t)grow * H_DIM + col] = v;
        else if (grow < count) y[(size_t)(base + grow) * H_DIM + col] = v;
      }
}

__global__ __launch_bounds__(256) void k_combine(
    const float* __restrict__ y, const int* __restrict__ counts,
    const int* __restrict__ tE, const int* __restrict__ tP,
    const float* __restrict__ tG, float* __restrict__ out) {
  int t = blockIdx.x;
  int c = threadIdx.x;  // H/4 = 256 float4 per token row
  int bases[NE];
  int s = 0;
#pragma unroll
  for (int e = 0; e < NE; e++) { bases[e] = s; s += counts[e]; }
  int e0 = tE[t * 2], e1 = tE[t * 2 + 1];
  int r0 = bases[e0] + tP[t * 2], r1 = bases[e1] + tP[t * 2 + 1];
  float g0 = tG[t * 2], g1 = tG[t * 2 + 1];
  const float4* y4 = (const float4*)y;
  float4* o4 = (float4*)out;
  float4 sv = o4[(size_t)t * (H_DIM / 4) + c];
  float4 a = y4[(size_t)r0 * (H_DIM / 4) + c];
  float4 b = y4[(size_t)r1 * (H_DIM / 4) + c];
  sv.x += g0 * a.x + g1 * b.x;
  sv.y += g0 * a.y + g1 * b.y;
  sv.z += g0 * a.z + g1 * b.z;
  sv.w += g0 * a.w + g1 * b.w;
  o4[(size_t)t * (H_DIM / 4) + c] = sv;
}

extern "C" void kernel_launch(void* const* d_in, const int* in_sizes, int n_in,
                              void* d_out, int out_size, void* d_ws, size_t ws_size,
                              hipStream_t stream) {
  const float* x = (const float*)d_in[0];
  const float* sg_w = (const float*)d_in[1];
  const float* su_w = (const float*)d_in[2];
  const float* sd_w = (const float*)d_in[3];
  const float* router_w = (const float*)d_in[4];
  const float* routing_bias = (const float*)d_in[5];
  const float* wg = (const float*)d_in[6];
  const float* wu = (const float*)d_in[7];
  const float* wd = (const float*)d_in[8];
  float* out = (float*)d_out;
  char* ws = (char*)d_ws;

  __bf16* xb  = (__bf16*)(ws + 0);            //  8,388,608
  __bf16* hs  = (__bf16*)(ws + 8388608);      // 16,777,216
  __bf16* hr  = (__bf16*)(ws + 25165824);     // 33,554,432
  float*  y   = (float*)(ws + 58720256);      // 33,554,432
  __bf16* wgb = (__bf16*)(ws + 92274688);     // 33,554,432
  __bf16* wub = (__bf16*)(ws + 125829120);    // 33,554,432
  __bf16* wdb = (__bf16*)(ws + 159383552);    // 33,554,432
  __bf16* sgb = (__bf16*)(ws + 192937984);    //  4,194,304
  __bf16* sub = (__bf16*)(ws + 197132288);    //  4,194,304
  __bf16* sdb = (__bf16*)(ws + 201326592);    //  4,194,304
  int* counts = (int*)(ws + 205520896);
  int* list   = (int*)(ws + 205520960);       // 131,072
  int* tE     = (int*)(ws + 205652032);       // 32,768
  int* tP     = (int*)(ws + 205684800);       // 32,768
  float* tG   = (float*)(ws + 205717568);     // 32,768

  hipMemsetAsync(counts, 0, NE * sizeof(int), stream);
  k_castall<<<27648, 256, 0, stream>>>(wg, wu, wd, sg_w, su_w, sd_w,
                                       wgb, wub, wdb, sgb, sub, sdb);
  k_router<<<NT / 4, 256, 0, stream>>>(x, router_w, routing_bias, xb,
                                       counts, list, tE, tP, tG);
  dim3 gu(I_DIM / 128, NT / 256, NE + 1);
  k_upgate8<<<gu, 512, 0, stream>>>(xb, wgb, wub, sgb, sub, counts, list, hs, hr);
  dim3 gd(H_DIM / 128, NT / 128, NE + 1);
  k_down97<<<gd, 256, 0, stream>>>(hs, hr, wdb, sdb, counts, out, y);
  k_combine<<<NT, 256, 0, stream>>>(y, counts, tE, tP, tG, out);
}

// Round 9
// 382.583 us; speedup vs baseline: 1.5525x; 1.0204x over previous
//
#include <hip/hip_runtime.h>
#include <hip/hip_bf16.h>

#define H_DIM 1024
#define I_DIM 2048
#define NE 8
#define NT 4096

typedef __bf16 bf16x8 __attribute__((ext_vector_type(8)));
typedef __bf16 bf16x4 __attribute__((ext_vector_type(4)));
typedef float f32x4 __attribute__((ext_vector_type(4)));

// 16B-chunk index within a [rows][8-chunk] LDS tile, XOR-swizzled (verified
// conflict-free R1-R8: SQ_LDS_BANK_CONFLICT == 0).
__device__ __forceinline__ int swzc(int r, int j) { return r * 8 + (j ^ (r & 7)); }

// async global->LDS, 16B per lane. LDS dest is wave-uniform base (HW adds lane*16).
__device__ __forceinline__ void gl16(const void* g, void* l) {
  __builtin_amdgcn_global_load_lds(
      (const __attribute__((address_space(1))) unsigned int*)g,
      (__attribute__((address_space(3))) unsigned int*)l, 16, 0, 0);
}

__device__ __forceinline__ bf16x8 cvt8(float4 a, float4 b) {
  bf16x8 r;
  r[0] = (__bf16)a.x; r[1] = (__bf16)a.y; r[2] = (__bf16)a.z; r[3] = (__bf16)a.w;
  r[4] = (__bf16)b.x; r[5] = (__bf16)b.y; r[6] = (__bf16)b.z; r[7] = (__bf16)b.w;
  return r;
}

// Fused prep: blocks [0, 27648) cast all six weight matrices fp32->bf16;
// blocks [27648, 28672) run the router (independent work, overlapped).
__global__ __launch_bounds__(256) void k_prep(
    const float* __restrict__ wg, const float* __restrict__ wu,
    const float* __restrict__ wd, const float* __restrict__ sg,
    const float* __restrict__ su, const float* __restrict__ sd,
    __bf16* __restrict__ wgb, __bf16* __restrict__ wub, __bf16* __restrict__ wdb,
    __bf16* __restrict__ sgb, __bf16* __restrict__ sub, __bf16* __restrict__ sdb,
    const float* __restrict__ x, const float* __restrict__ rw,
    const float* __restrict__ rbias, __bf16* __restrict__ xb,
    int* __restrict__ counts, int* __restrict__ list,
    int* __restrict__ tE, int* __restrict__ tP, float* __restrict__ tG) {
  if (blockIdx.x < 27648) {
    // ---- weight cast ----
    long long i = (long long)blockIdx.x * 256 + threadIdx.x;
    const long long NW = 1LL << 21, NS = 1LL << 18;
    const float* s; __bf16* d; int off;
    if (i < 3 * NW) {
      int r = (int)(i >> 21); off = (int)(i & (NW - 1));
      s = (r == 0) ? wg : (r == 1) ? wu : wd;
      d = (r == 0) ? wgb : (r == 1) ? wub : wdb;
    } else {
      long long j = i - 3 * NW;
      int r = (int)(j >> 18); off = (int)(j & (NS - 1));
      s = (r == 0) ? sg : (r == 1) ? su : sd;
      d = (r == 0) ? sgb : (r == 1) ? sub : sdb;
    }
    const float4* s4 = (const float4*)s;
    float4 a = s4[(size_t)off * 2], b = s4[(size_t)off * 2 + 1];
    ((bf16x8*)d)[off] = cvt8(a, b);
    return;
  }
  // ---- router (sigmoid top-2 renorm + per-expert lists; fuses x->bf16) ----
  int blk = blockIdx.x - 27648;               // 0..1023
  int wv = threadIdx.x >> 6, lane = threadIdx.x & 63;
  int t = blk * 4 + wv;
  float acc[NE];
#pragma unroll
  for (int e = 0; e < NE; e++) acc[e] = 0.f;
  const float4* xr = (const float4*)(x + (size_t)t * H_DIM);
  const float4* wr4 = (const float4*)rw;
  bf16x4* xo = (bf16x4*)xb + (size_t)t * (H_DIM / 4);
#pragma unroll
  for (int it = 0; it < 4; ++it) {
    int c = it * 64 + lane;
    float4 xv = xr[c];
    bf16x4 bv;
    bv[0] = (__bf16)xv.x; bv[1] = (__bf16)xv.y;
    bv[2] = (__bf16)xv.z; bv[3] = (__bf16)xv.w;
    xo[c] = bv;
#pragma unroll
    for (int e = 0; e < NE; e++) {
      float4 wv2 = wr4[e * (H_DIM / 4) + c];
      acc[e] += xv.x * wv2.x + xv.y * wv2.y + xv.z * wv2.z + xv.w * wv2.w;
    }
  }
#pragma unroll
  for (int e = 0; e < NE; e++) {
#pragma unroll
    for (int off = 32; off > 0; off >>= 1) acc[e] += __shfl_xor(acc[e], off, 64);
  }
  if (lane == 0) {
    float p[NE];
#pragma unroll
    for (int e = 0; e < NE; e++) p[e] = 1.f / (1.f + expf(-(acc[e] + rbias[e])));
    int e0 = 0;
#pragma unroll
    for (int e = 1; e < NE; e++) if (p[e] > p[e0]) e0 = e;
    int e1 = -1;
#pragma unroll
    for (int e = 0; e < NE; e++) if (e != e0 && (e1 < 0 || p[e] > p[e1])) e1 = e;
    float s = p[e0] + p[e1];
    float g0 = p[e0] / s, g1 = p[e1] / s;
    int p0 = atomicAdd(&counts[e0], 1);
    int p1 = atomicAdd(&counts[e1], 1);
    list[e0 * NT + p0] = t;
    list[e1 * NT + p1] = t;
    tE[t * 2] = e0; tE[t * 2 + 1] = e1;
    tP[t * 2] = p0; tP[t * 2 + 1] = p1;
    tG[t * 2] = g0; tG[t * 2 + 1] = g1;
  }
}

// ---------------------------------------------------------------------------
// Fused gate+up GEMM, m97 config: tile 128 token-rows x 64 i-cols x {g,u}
// (B-tile = 128 rows: b = wc*64 + gu*32 + c -> (gu?u:g) col n0+wc*32+c),
// BK=64, 4 waves (2x2), 64 KB dbuf LDS -> 2 blocks/CU. dim3 grid, n fastest.
// Each wave's acc[m][0..1] = g cols, acc[m][2..3] = u cols (same cols) ->
// silu pairing is lane-local.
// ---------------------------------------------------------------------------
__global__ __launch_bounds__(256, 2) void k_upgate97(
    const __bf16* __restrict__ xb, const __bf16* __restrict__ wgb,
    const __bf16* __restrict__ wub, const __bf16* __restrict__ sgb,
    const __bf16* __restrict__ sub, const int* __restrict__ counts,
    const int* __restrict__ list,
    __bf16* __restrict__ hs, __bf16* __restrict__ hr) {
  int z = blockIdx.z;
  int m0 = blockIdx.y * 128, n0 = blockIdx.x * 64;
  bool sh = (z == NE);
  int count, base = 0;
  const __bf16 *Bg, *Bu;
  if (sh) {
    count = NT; Bg = sgb; Bu = sub;
  } else {
    count = counts[z];
    if (m0 >= count) return;
    for (int e = 0; e < z; e++) base += counts[e];
    Bg = wgb + (size_t)z * (I_DIM * H_DIM);
    Bu = wub + (size_t)z * (I_DIM * H_DIM);
  }

  __shared__ bf16x8 lds[4096];   // [2][A 1024 | B 1024] = 64 KB

  int tid = threadIdx.x, lane = tid & 63, w = tid >> 6;
  int wr = w >> 1, wc = w & 1;
  int fr = lane & 15, fs = lane >> 4;

  const bf16x8* a8 = (const bf16x8*)xb;
  const bf16x8* g8 = (const bf16x8*)Bg;
  const bf16x8* u8 = (const bf16x8*)Bu;

  const bf16x8* pA[4];
  const bf16x8* pB[4];
#pragma unroll
  for (int q = 0; q < 4; q++) {
    int c = q * 256 + tid;                  // chunk 0..1023 (128 rows x 8)
    int r = c >> 3, j = (c & 7) ^ (r & 7);
    int gr = m0 + r;
    int tok = sh ? gr : ((gr < count) ? list[z * NT + gr] : list[z * NT]);
    pA[q] = a8 + (size_t)tok * (H_DIM / 8) + j;
    int G = r >> 6, gu = (r >> 5) & 1, cc = r & 31;
    pB[q] = (gu ? u8 : g8) + (size_t)(n0 + G * 32 + cc) * (H_DIM / 8) + j;
  }

  f32x4 acc[4][4];
#pragma unroll
  for (int m = 0; m < 4; m++)
#pragma unroll
    for (int n = 0; n < 4; n++) acc[m][n] = (f32x4){0.f, 0.f, 0.f, 0.f};

  // prologue: stage tile 0 into buf 0
  {
    bf16x8* dA = lds;
    bf16x8* dB = lds + 1024;
#pragma unroll
    for (int q = 0; q < 4; q++) {
      gl16(pA[q], dA + q * 256 + w * 64);
      gl16(pB[q], dB + q * 256 + w * 64);
    }
  }

  const int NK = H_DIM / 64;  // 16
  for (int kt = 0; kt < NK; ++kt) {
    __syncthreads();           // drains tile kt's loads; WAR-fences buf^1
    if (kt + 1 < NK) {
      bf16x8* dA = lds + ((kt + 1) & 1) * 2048;
      bf16x8* dB = dA + 1024;
      int ko = (kt + 1) * 8;
#pragma unroll
      for (int q = 0; q < 4; q++) {
        gl16(pA[q] + ko, dA + q * 256 + w * 64);
        gl16(pB[q] + ko, dB + q * 256 + w * 64);
      }
    }
    const bf16x8* Ac = lds + (kt & 1) * 2048;
    const bf16x8* Bc = Ac + 1024;
#pragma unroll
    for (int ks = 0; ks < 2; ks++) {
      bf16x8 af[4], bfr[4];
#pragma unroll
      for (int mf = 0; mf < 4; mf++) af[mf] = Ac[swzc(wr * 64 + mf * 16 + fr, ks * 4 + fs)];
#pragma unroll
      for (int nf = 0; nf < 4; nf++) bfr[nf] = Bc[swzc(wc * 64 + nf * 16 + fr, ks * 4 + fs)];
      __builtin_amdgcn_s_setprio(1);
#pragma unroll
      for (int m = 0; m < 4; m++)
#pragma unroll
        for (int n = 0; n < 4; n++)
          acc[m][n] = __builtin_amdgcn_mfma_f32_16x16x32_bf16(af[m], bfr[n], acc[m][n], 0, 0, 0);
      __builtin_amdgcn_s_setprio(0);
    }
  }

  // epilogue: h = silu(g)*u; g = acc[m][np], u = acc[m][np+2]
#pragma unroll
  for (int m = 0; m < 4; m++)
#pragma unroll
    for (int np = 0; np < 2; np++)
#pragma unroll
      for (int q2 = 0; q2 < 4; q2++) {
        int row = wr * 64 + m * 16 + fs * 4 + q2;
        int col = n0 + wc * 32 + np * 16 + fr;
        float g = acc[m][np][q2], u = acc[m][np + 2][q2];
        float h = g * u / (1.f + expf(-g));
        __bf16 hb = (__bf16)h;
        int grow = m0 + row;
        if (sh) hs[(size_t)grow * I_DIM + col] = hb;
        else if (grow < count) hr[(size_t)(base + grow) * I_DIM + col] = hb;
      }
}

// ---------------------------------------------------------------------------
// Down GEMM, m97 config: 128x128 tile, BK=64, 4 waves (2x2), 64 KB dbuf LDS
// -> 2 blocks/CU. dim3 grid (n=8, m=32, z=9), n fastest, NO swizzle.
// ---------------------------------------------------------------------------
__global__ __launch_bounds__(256, 2) void k_down97(
    const __bf16* __restrict__ hs, const __bf16* __restrict__ hr,
    const __bf16* __restrict__ wdb, const __bf16* __restrict__ sdb,
    const int* __restrict__ counts,
    float* __restrict__ out, float* __restrict__ y) {
  int z = blockIdx.z;
  int m0 = blockIdx.y * 128, n0 = blockIdx.x * 128;
  bool sh = (z == NE);
  int count, base = 0;
  const __bf16 *B, *A;
  if (sh) {
    count = NT; B = sdb; A = hs;
  } else {
    count = counts[z];
    if (m0 >= count) return;
    for (int e = 0; e < z; e++) base += counts[e];
    B = wdb + (size_t)z * (H_DIM * I_DIM);
    A = hr + (size_t)base * I_DIM;
  }

  __shared__ bf16x8 lds[4096];   // [2][A 1024 | B 1024] = 64 KB

  int tid = threadIdx.x, lane = tid & 63, w = tid >> 6;
  int wr = w >> 1, wc = w & 1;
  int fr = lane & 15, fs = lane >> 4;

  const bf16x8* a8 = (const bf16x8*)A;
  const bf16x8* b8 = (const bf16x8*)B;

  const bf16x8* pA[4];
  const bf16x8* pB[4];
#pragma unroll
  for (int q = 0; q < 4; q++) {
    int c = q * 256 + tid;                  // chunk 0..1023 (128 rows x 8)
    int r = c >> 3, j = (c & 7) ^ (r & 7);
    int ra = m0 + r; if (ra >= count) ra = count - 1;
    pA[q] = a8 + (size_t)ra * (I_DIM / 8) + j;
    pB[q] = b8 + (size_t)(n0 + r) * (I_DIM / 8) + j;
  }

  f32x4 acc[4][4];
#pragma unroll
  for (int m = 0; m < 4; m++)
#pragma unroll
    for (int n = 0; n < 4; n++) acc[m][n] = (f32x4){0.f, 0.f, 0.f, 0.f};

  // prologue: stage tile 0 into buf 0
  {
    bf16x8* dA = lds;
    bf16x8* dB = lds + 1024;
#pragma unroll
    for (int q = 0; q < 4; q++) {
      gl16(pA[q], dA + q * 256 + w * 64);
      gl16(pB[q], dB + q * 256 + w * 64);
    }
  }

  const int NK = I_DIM / 64;  // 32
  for (int kt = 0; kt < NK; ++kt) {
    __syncthreads();           // drains tile kt's loads; WAR-fences buf^1
    if (kt + 1 < NK) {
      bf16x8* dA = lds + ((kt + 1) & 1) * 2048;
      bf16x8* dB = dA + 1024;
      int ko = (kt + 1) * 8;
#pragma unroll
      for (int q = 0; q < 4; q++) {
        gl16(pA[q] + ko, dA + q * 256 + w * 64);
        gl16(pB[q] + ko, dB + q * 256 + w * 64);
      }
    }
    const bf16x8* Ac = lds + (kt & 1) * 2048;
    const bf16x8* Bc = Ac + 1024;
#pragma unroll
    for (int ks = 0; ks < 2; ks++) {
      bf16x8 af[4], bfr[4];
#pragma unroll
      for (int mf = 0; mf < 4; mf++) af[mf] = Ac[swzc(wr * 64 + mf * 16 + fr, ks * 4 + fs)];
#pragma unroll
      for (int nf = 0; nf < 4; nf++) bfr[nf] = Bc[swzc(wc * 64 + nf * 16 + fr, ks * 4 + fs)];
      __builtin_amdgcn_s_setprio(1);
#pragma unroll
      for (int m = 0; m < 4; m++)
#pragma unroll
        for (int n = 0; n < 4; n++)
          acc[m][n] = __builtin_amdgcn_mfma_f32_16x16x32_bf16(af[m], bfr[n], acc[m][n], 0, 0, 0);
      __builtin_amdgcn_s_setprio(0);
    }
  }

#pragma unroll
  for (int m = 0; m < 4; m++)
#pragma unroll
    for (int n = 0; n < 4; n++)
#pragma unroll
      for (int q2 = 0; q2 < 4; q2++) {
        int row = wr * 64 + m * 16 + fs * 4 + q2;
        int col = n0 + wc * 64 + n * 16 + fr;
        float v = acc[m][n][q2];
        int grow = m0 + row;
        if (sh) out[(size_t)grow * H_DIM + col] = v;
        else if (grow < count) y[(size_t)(base + grow) * H_DIM + col] = v;
      }
}

__global__ __launch_bounds__(256) void k_combine(
    const float* __restrict__ y, const int* __restrict__ counts,
    const int* __restrict__ tE, const int* __restrict__ tP,
    const float* __restrict__ tG, float* __restrict__ out) {
  int t = blockIdx.x;
  int c = threadIdx.x;  // H/4 = 256 float4 per token row
  int bases[NE];
  int s = 0;
#pragma unroll
  for (int e = 0; e < NE; e++) { bases[e] = s; s += counts[e]; }
  int e0 = tE[t * 2], e1 = tE[t * 2 + 1];
  int r0 = bases[e0] + tP[t * 2], r1 = bases[e1] + tP[t * 2 + 1];
  float g0 = tG[t * 2], g1 = tG[t * 2 + 1];
  const float4* y4 = (const float4*)y;
  float4* o4 = (float4*)out;
  float4 sv = o4[(size_t)t * (H_DIM / 4) + c];
  float4 a = y4[(size_t)r0 * (H_DIM / 4) + c];
  float4 b = y4[(size_t)r1 * (H_DIM / 4) + c];
  sv.x += g0 * a.x + g1 * b.x;
  sv.y += g0 * a.y + g1 * b.y;
  sv.z += g0 * a.z + g1 * b.z;
  sv.w += g0 * a.w + g1 * b.w;
  o4[(size_t)t * (H_DIM / 4) + c] = sv;
}

extern "C" void kernel_launch(void* const* d_in, const int* in_sizes, int n_in,
                              void* d_out, int out_size, void* d_ws, size_t ws_size,
                              hipStream_t stream) {
  const float* x = (const float*)d_in[0];
  const float* sg_w = (const float*)d_in[1];
  const float* su_w = (const float*)d_in[2];
  const float* sd_w = (const float*)d_in[3];
  const float* router_w = (const float*)d_in[4];
  const float* routing_bias = (const float*)d_in[5];
  const float* wg = (const float*)d_in[6];
  const float* wu = (const float*)d_in[7];
  const float* wd = (const float*)d_in[8];
  float* out = (float*)d_out;
  char* ws = (char*)d_ws;

  __bf16* xb  = (__bf16*)(ws + 0);            //  8,388,608
  __bf16* hs  = (__bf16*)(ws + 8388608);      // 16,777,216
  __bf16* hr  = (__bf16*)(ws + 25165824);     // 33,554,432
  float*  y   = (float*)(ws + 58720256);      // 33,554,432
  __bf16* wgb = (__bf16*)(ws + 92274688);     // 33,554,432
  __bf16* wub = (__bf16*)(ws + 125829120);    // 33,554,432
  __bf16* wdb = (__bf16*)(ws + 159383552);    // 33,554,432
  __bf16* sgb = (__bf16*)(ws + 192937984);    //  4,194,304
  __bf16* sub = (__bf16*)(ws + 197132288);    //  4,194,304
  __bf16* sdb = (__bf16*)(ws + 201326592);    //  4,194,304
  int* counts = (int*)(ws + 205520896);
  int* list   = (int*)(ws + 205520960);       // 131,072
  int* tE     = (int*)(ws + 205652032);       // 32,768
  int* tP     = (int*)(ws + 205684800);       // 32,768
  float* tG   = (float*)(ws + 205717568);     // 32,768

  hipMemsetAsync(counts, 0, NE * sizeof(int), stream);
  k_prep<<<27648 + NT / 4, 256, 0, stream>>>(
      wg, wu, wd, sg_w, su_w, sd_w, wgb, wub, wdb, sgb, sub, sdb,
      x, router_w, routing_bias, xb, counts, list, tE, tP, tG);
  dim3 gu(I_DIM / 64, NT / 128, NE + 1);
  k_upgate97<<<gu, 256, 0, stream>>>(xb, wgb, wub, sgb, sub, counts, list, hs, hr);
  dim3 gd(H_DIM / 128, NT / 128, NE + 1);
  k_down97<<<gd, 256, 0, stream>>>(hs, hr, wdb, sdb, counts, out, y);
  k_combine<<<NT, 256, 0, stream>>>(y, counts, tE, tP, tG, out);
}